// Round 2
// baseline (860.062 us; speedup 1.0000x reference)
//
#include <hip/hip_runtime.h>

// DynamicSparseScaledDotProductAttention on MI355X (gfx950) — round 2
// q,k,v: [32, 2048, 64] fp32; gate_w: [1,64]; gate_b: [1]
// outputs (tuple): out [32,2048,64] fp32, attn [32,2048,2048] fp32
//
// Structure: prep kernels convert K -> bf16 [bh][key][d] and V -> bf16
// transposed [bh][d][key] in d_ws. These layouts ARE the MFMA B-frag order,
// so the main kernel loads fragments straight from global (L2-resident,
// 512 KB/head) with dwordx4 — no LDS staging, no __syncthreads in the hot
// loop. Each wave handles 16 queries fully independently:
//   pass 1: QK MFMA + masked exp -> softmax denominators (no max needed,
//           |s| <= ~8 so exp is safe in fp32)
//   pass 2: recompute QK, normalize, C->A transpose via per-wave LDS
//           (doubles as coalesced attn store), PV MFMA.
//
// MFMA mfma_f32_16x16x32_bf16 layouts (HW-verified per guide):
//   A-frag: lane holds A[m=lane&15][k=(lane>>4)*8 + j], j=0..7
//   B-frag: lane holds B[k=(lane>>4)*8+j][n=lane&15]
//   C/D   : lane holds D[row=(lane>>4)*4 + r][col=lane&15], r=0..3

typedef short bf16x8 __attribute__((ext_vector_type(8)));
typedef float f32x4  __attribute__((ext_vector_type(4)));

#define BH   32
#define LSEQ 2048
#define DDIM 64
#define PB_STRIDE 36   // Pbuf row stride (f32); 144B rows

__device__ __forceinline__ unsigned short f2bf(float x) {
    unsigned int u = __float_as_uint(x);
    u += 0x7FFFu + ((u >> 16) & 1u);
    return (unsigned short)(u >> 16);
}

// ---- prep 1: K fp32 [bh][key][d] -> bf16 same layout ----
__global__ __launch_bounds__(256)
void conv_k_kernel(const float* __restrict__ K, unsigned short* __restrict__ Kb)
{
    const size_t i = ((size_t)blockIdx.x * 256 + threadIdx.x) * 8;
    f32x4 a = *(const f32x4*)(K + i);
    f32x4 b = *(const f32x4*)(K + i + 4);
    ushort4 lo, hi;
    lo.x = f2bf(a[0]); lo.y = f2bf(a[1]); lo.z = f2bf(a[2]); lo.w = f2bf(a[3]);
    hi.x = f2bf(b[0]); hi.y = f2bf(b[1]); hi.z = f2bf(b[2]); hi.w = f2bf(b[3]);
    *(ushort4*)(Kb + i)     = lo;
    *(ushort4*)(Kb + i + 4) = hi;
}

// ---- prep 2: V fp32 [bh][key][d] -> bf16 transposed [bh][d][key] ----
__global__ __launch_bounds__(256)
void conv_vt_kernel(const float* __restrict__ V, unsigned short* __restrict__ Vt)
{
    __shared__ float tile[64][65];
    const int bh   = blockIdx.x >> 5;
    const int key0 = (blockIdx.x & 31) << 6;
    const int tid  = threadIdx.x;

    const float* src = V + ((size_t)bh * LSEQ + key0) * DDIM;
    #pragma unroll
    for (int i = 0; i < 4; ++i) {
        const int f   = tid + 256 * i;      // float4 index within 64x64 tile
        const int row = f >> 4;             // key within tile
        const int c4  = f & 15;             // float4 within row
        f32x4 x = *(const f32x4*)(src + row * DDIM + c4 * 4);
        tile[row][c4 * 4 + 0] = x[0];
        tile[row][c4 * 4 + 1] = x[1];
        tile[row][c4 * 4 + 2] = x[2];
        tile[row][c4 * 4 + 3] = x[3];
    }
    __syncthreads();
    const int d    = tid >> 2;              // 0..63
    const int kseg = (tid & 3) << 4;        // 0,16,32,48
    unsigned short* dst = Vt + ((size_t)bh * DDIM + d) * LSEQ + key0 + kseg;
    ushort4 o[4];
    #pragma unroll
    for (int j = 0; j < 16; ++j)
        ((unsigned short*)o)[j] = f2bf(tile[kseg + j][d]);
    #pragma unroll
    for (int j = 0; j < 4; ++j) *(ushort4*)(dst + j * 4) = o[j];
}

// ---- main kernel: barrier-free per-wave attention ----
__global__ __launch_bounds__(256)
void dsa_attn_kernel(const float* __restrict__ Q,
                     const unsigned short* __restrict__ Kb,
                     const unsigned short* __restrict__ Vt,
                     const float* __restrict__ GW,
                     const float* __restrict__ GB,
                     float* __restrict__ OUT,
                     float* __restrict__ ATT)
{
    __shared__ float Pbuf[4][16 * PB_STRIDE];   // per-wave, no cross-wave sharing

    const int bx   = blockIdx.x;
    const int bh   = bx >> 5;
    const int q0   = (bx & 31) << 6;
    const int tid  = threadIdx.x;
    const int wave = tid >> 6;
    const int lane = tid & 63;
    const int m16  = lane & 15;
    const int quad = lane >> 4;
    const int qw   = q0 + (wave << 4);          // first of this wave's 16 queries

    const float* qr = Q + ((size_t)bh * LSEQ + qw + m16) * DDIM;
    const unsigned short* kbh = Kb + (size_t)bh * LSEQ * DDIM;
    const unsigned short* vbh = Vt + (size_t)bh * DDIM * LSEQ;

    // ---- Q A-frags (bf16) + exact fp32 gate, all in-wave ----
    bf16x8 qfrag[2];
    #pragma unroll
    for (int db = 0; db < 2; ++db) {
        const float* p = qr + db * 32 + (quad << 3);
        bf16x8 f;
        #pragma unroll
        for (int j = 0; j < 8; ++j) f[j] = (short)f2bf(p[j]);
        qfrag[db] = f;
    }
    float g = 0.f;
    {
        const float* p = qr + (quad << 4);
        #pragma unroll
        for (int j = 0; j < 16; ++j) g += p[j] * GW[(quad << 4) + j];
        g += __shfl_xor(g, 16);
        g += __shfl_xor(g, 32);
        g += GB[0];            // every lane now holds gate-logit for query m16
    }
    bool  gate[4];
    int   irow[4];
    #pragma unroll
    for (int r = 0; r < 4; ++r) {
        const int row = (quad << 2) + r;
        gate[r] = __shfl(g, row) > 0.f;     // sigmoid(x)>0.5 <=> x>0
        irow[r] = qw + row;
    }

    // =============== pass 1: softmax denominators ===============
    float lsum[4] = {0.f, 0.f, 0.f, 0.f};
    #pragma unroll 2
    for (int kt = 0; kt < LSEQ / 32; ++kt) {
        #pragma unroll
        for (int nt = 0; nt < 2; ++nt) {
            const int keyb = kt * 32 + nt * 16;
            const unsigned short* kp = kbh + (size_t)(keyb + m16) * DDIM + (quad << 3);
            bf16x8 kf0 = *(const bf16x8*)(kp);
            bf16x8 kf1 = *(const bf16x8*)(kp + 32);
            f32x4 acc = {0.f, 0.f, 0.f, 0.f};
            acc = __builtin_amdgcn_mfma_f32_16x16x32_bf16(qfrag[0], kf0, acc, 0, 0, 0);
            acc = __builtin_amdgcn_mfma_f32_16x16x32_bf16(qfrag[1], kf1, acc, 0, 0, 0);
            const int jcol = keyb + m16;
            #pragma unroll
            for (int r = 0; r < 4; ++r) {
                int dist = irow[r] - jcol; if (dist < 0) dist = -dist;
                const bool allowed = gate[r] || (dist <= 2);
                lsum[r] += allowed ? __expf(acc[r] * 0.125f) : 0.f;
            }
        }
    }
    float linv[4];
    #pragma unroll
    for (int r = 0; r < 4; ++r) {
        float x = lsum[r];
        x += __shfl_xor(x, 1);
        x += __shfl_xor(x, 2);
        x += __shfl_xor(x, 4);
        x += __shfl_xor(x, 8);
        linv[r] = 1.0f / x;
    }

    // =============== pass 2: recompute, write attn, accumulate P·V ===============
    f32x4 oacc[4];
    #pragma unroll
    for (int dt = 0; dt < 4; ++dt) oacc[dt] = (f32x4){0.f, 0.f, 0.f, 0.f};

    float* prow = &Pbuf[wave][0];
    #pragma unroll 2
    for (int kt = 0; kt < LSEQ / 32; ++kt) {
        #pragma unroll
        for (int nt = 0; nt < 2; ++nt) {
            const int keyb = kt * 32 + nt * 16;
            const unsigned short* kp = kbh + (size_t)(keyb + m16) * DDIM + (quad << 3);
            bf16x8 kf0 = *(const bf16x8*)(kp);
            bf16x8 kf1 = *(const bf16x8*)(kp + 32);
            f32x4 acc = {0.f, 0.f, 0.f, 0.f};
            acc = __builtin_amdgcn_mfma_f32_16x16x32_bf16(qfrag[0], kf0, acc, 0, 0, 0);
            acc = __builtin_amdgcn_mfma_f32_16x16x32_bf16(qfrag[1], kf1, acc, 0, 0, 0);
            const int jcol = keyb + m16;
            #pragma unroll
            for (int r = 0; r < 4; ++r) {
                int dist = irow[r] - jcol; if (dist < 0) dist = -dist;
                const bool allowed = gate[r] || (dist <= 2);
                const float p = allowed ? __expf(acc[r] * 0.125f) * linv[r] : 0.f;
                prow[(((quad << 2) + r) * PB_STRIDE) + nt * 16 + m16] = p;
            }
        }
        // C-layout -> A-layout via per-wave LDS (compiler orders via lgkmcnt)
        const float* pr = prow + m16 * PB_STRIDE + (quad << 3);
        f32x4 p0 = *(const f32x4*)(pr);
        f32x4 p1 = *(const f32x4*)(pr + 4);

        float* ap = ATT + ((size_t)bh * LSEQ + qw + m16) * LSEQ + kt * 32 + (quad << 3);
        __builtin_nontemporal_store(p0, (f32x4*)(ap));
        __builtin_nontemporal_store(p1, (f32x4*)(ap + 4));

        bf16x8 pf;
        #pragma unroll
        for (int j = 0; j < 4; ++j) {
            pf[j]     = (short)f2bf(p0[j]);
            pf[4 + j] = (short)f2bf(p1[j]);
        }
        #pragma unroll
        for (int dt = 0; dt < 4; ++dt) {
            const unsigned short* vp = vbh + (size_t)(dt * 16 + m16) * LSEQ + kt * 32 + (quad << 3);
            bf16x8 vf = *(const bf16x8*)(vp);
            oacc[dt] = __builtin_amdgcn_mfma_f32_16x16x32_bf16(pf, vf, oacc[dt], 0, 0, 0);
        }
    }

    // epilogue: out rows in C-layout
    float* ob = OUT + ((size_t)bh * LSEQ + qw) * DDIM;
    #pragma unroll
    for (int dt = 0; dt < 4; ++dt) {
        #pragma unroll
        for (int r = 0; r < 4; ++r) {
            ob[((quad << 2) + r) * DDIM + dt * 16 + m16] = oacc[dt][r];
        }
    }
}

extern "C" void kernel_launch(void* const* d_in, const int* in_sizes, int n_in,
                              void* d_out, int out_size, void* d_ws, size_t ws_size,
                              hipStream_t stream) {
    const float* q  = (const float*)d_in[0];
    const float* k  = (const float*)d_in[1];
    const float* v  = (const float*)d_in[2];
    const float* gw = (const float*)d_in[3];
    const float* gb = (const float*)d_in[4];

    float* out  = (float*)d_out;                          // [32,2048,64]
    float* attn = out + (size_t)BH * LSEQ * DDIM;         // [32,2048,2048]

    unsigned short* Kb = (unsigned short*)d_ws;                           // 8 MB
    unsigned short* Vt = Kb + (size_t)BH * LSEQ * DDIM;                   // 8 MB

    const size_t nelem = (size_t)BH * LSEQ * DDIM;        // 4,194,304
    conv_k_kernel <<<dim3(nelem / (256 * 8)), dim3(256), 0, stream>>>(k, Kb);
    conv_vt_kernel<<<dim3(BH * (LSEQ / 64)),  dim3(256), 0, stream>>>(v, Vt);

    dsa_attn_kernel<<<dim3(BH * (LSEQ / 64)), dim3(256), 0, stream>>>(
        q, Kb, Vt, gw, gb, out, attn);
}